// Round 1
// baseline (90729.523 us; speedup 1.0000x reference)
//
#include <hip/hip_runtime.h>
#include <stdint.h>

#define BATCH 256
#define SEQT  512
#define DIM   128
#define HID   256
#define G3    768   // 3*HID

typedef unsigned short u16;
typedef unsigned int   u32;
typedef u16 u16x8 __attribute__((ext_vector_type(8)));
typedef u32 u32x4 __attribute__((ext_vector_type(4)));

static __device__ __forceinline__ float bf2f(u16 u) {
  u32 v = ((u32)u) << 16;
  return __builtin_bit_cast(float, v);
}
static __device__ __forceinline__ u16 f2bf(float f) {
  u32 x = __builtin_bit_cast(u32, f);
  x += 0x7FFFu + ((x >> 16) & 1u);
  return (u16)(x >> 16);
}
static __device__ __forceinline__ float sigm(float v) {
  return 1.f / (1.f + __expf(-v));
}

// ---------------- weight fp32 -> bf16 conversion ----------------
__global__ void convertk(const float* __restrict__ src, u16* __restrict__ dst, int n) {
  int i = blockIdx.x * 256 + threadIdx.x;
  if (i < n) dst[i] = f2bf(src[i]);
}

// ---------------- phase B: memory GRU, one workgroup per batch row ----------------
__launch_bounds__(256, 1)
__global__ void gru_mem(const float* __restrict__ x,
                        const u16* __restrict__ Wib, const u16* __restrict__ Whb,
                        const float* __restrict__ bmi, const float* __restrict__ bmh,
                        u16* __restrict__ mem) {
  const int b = blockIdx.x, tid = threadIdx.x;
  __shared__ float hs[HID];
  __shared__ float xs[DIM];
  const float bir = bmi[tid],      biz = bmi[HID + tid],  bin = bmi[2*HID + tid];
  const float bhr = bmh[tid],      bhz = bmh[HID + tid],  bhn = bmh[2*HID + tid];
  const u16* wir = Wib + (size_t)tid * DIM;
  const u16* wiz = Wib + (size_t)(HID + tid) * DIM;
  const u16* win = Wib + (size_t)(2*HID + tid) * DIM;
  const u16* whr = Whb + (size_t)tid * HID;
  const u16* whz = Whb + (size_t)(HID + tid) * HID;
  const u16* whn = Whb + (size_t)(2*HID + tid) * HID;
  hs[tid] = 0.f;
  float hprev = 0.f;
  __syncthreads();
  for (int t = 0; t < SEQT; ++t) {
    if (tid < DIM)
      xs[tid] = __builtin_nontemporal_load(x + ((size_t)b * SEQT + t) * DIM + tid);
    __syncthreads();
    // input-side projections (rows tid, H+tid, 2H+tid of Wm_i)
    float air = 0.f, aiz = 0.f, ain = 0.f;
    #pragma unroll 4
    for (int j = 0; j < DIM; j += 8) {
      u16x8 wa = *(const u16x8*)(wir + j);
      u16x8 wb = *(const u16x8*)(wiz + j);
      u16x8 wc = *(const u16x8*)(win + j);
      #pragma unroll
      for (int k = 0; k < 8; ++k) {
        float xv = xs[j + k];
        air += xv * bf2f(wa[k]);
        aiz += xv * bf2f(wb[k]);
        ain += xv * bf2f(wc[k]);
      }
    }
    // hidden-side projections
    float ahr = 0.f, ahz = 0.f, ahn = 0.f;
    #pragma unroll 4
    for (int j = 0; j < HID; j += 8) {
      u16x8 wa = *(const u16x8*)(whr + j);
      u16x8 wb = *(const u16x8*)(whz + j);
      u16x8 wc = *(const u16x8*)(whn + j);
      #pragma unroll
      for (int k = 0; k < 8; ++k) {
        float hv = hs[j + k];
        ahr += hv * bf2f(wa[k]);
        ahz += hv * bf2f(wb[k]);
        ahn += hv * bf2f(wc[k]);
      }
    }
    float r = sigm(air + bir + ahr + bhr);
    float z = sigm(aiz + biz + ahz + bhz);
    float n = tanhf(ain + bin + r * (ahn + bhn));
    float hnew = (1.f - z) * n + z * hprev;
    __syncthreads();               // all reads of hs done
    hs[tid] = hnew;
    hprev = hnew;
    mem[((size_t)b * SEQT + t) * HID + tid] = f2bf(hnew);
    __syncthreads();               // hs (and xs) ready / consumed
  }
}

// ---------------- GRU cell with h=0 (feed-forward): thread owns cols tid, H+tid, 2H+tid ----------------
template <int IN>
static __device__ __forceinline__ float cell_fwd(const float* __restrict__ in,
                                                 const u16* __restrict__ Wb, int tid,
                                                 float br_, float bz_, float bni, float bnh) {
  const u16* wr = Wb + (size_t)tid * IN;
  const u16* wz = Wb + (size_t)(HID + tid) * IN;
  const u16* wn = Wb + (size_t)(2*HID + tid) * IN;
  float ar = 0.f, az = 0.f, an = 0.f;
  #pragma unroll 4
  for (int j = 0; j < IN; j += 8) {
    u16x8 wa = *(const u16x8*)(wr + j);
    u16x8 wb = *(const u16x8*)(wz + j);
    u16x8 wc = *(const u16x8*)(wn + j);
    #pragma unroll
    for (int k = 0; k < 8; ++k) {
      float xv = in[j + k];
      ar += xv * bf2f(wa[k]);
      az += xv * bf2f(wb[k]);
      an += xv * bf2f(wc[k]);
    }
  }
  float r = sigm(ar + br_);
  float z = sigm(az + bz_);
  float n = tanhf(an + bni + r * bnh);
  return (1.f - z) * n;
}

// ---------------- phase C: decoder scan, one workgroup per batch row ----------------
#define LSTR 262   // 256 + 6: odd dword stride (131) -> 3*s bank rotation

__launch_bounds__(256, 1)
__global__ void decoder(const float* __restrict__ x, const u16* __restrict__ mem,
                        const u16* __restrict__ W0b, const u16* __restrict__ W1b,
                        const u16* __restrict__ W2b, const u16* __restrict__ W3b,
                        const u16* __restrict__ W4b,
                        const float* __restrict__ bi0, const float* __restrict__ bh0,
                        const float* __restrict__ bi1, const float* __restrict__ bh1,
                        const float* __restrict__ bi2, const float* __restrict__ bh2,
                        const float* __restrict__ bi3, const float* __restrict__ bh3,
                        const float* __restrict__ bi4, const float* __restrict__ bh4,
                        const float* __restrict__ Wo, const float* __restrict__ bo,
                        float* __restrict__ out) {
  const int b = blockIdx.x, tid = threadIdx.x;
  const int lane = tid & 63, wave = tid >> 6;
  const int sq = tid & 3, ss = tid >> 2;         // scores: quad sq handles 64 h-chunk of row ss
  __shared__ u16 L[64 * LSTR];                   // one 64x256 bf16 mem tile (padded)
  __shared__ float sc[64], pp[64], red[4];       // red[0]=alpha red[1]=l_run red[2]=m_run
  __shared__ float kst[HID];
  __shared__ float dv[DIM + HID];
  __shared__ float hb[2][HID];

  float Br[5], Bz[5], Bni[5], Bnh[5];
  Br[0] = bi0[tid] + bh0[tid]; Bz[0] = bi0[HID+tid] + bh0[HID+tid];
  Bni[0] = bi0[2*HID+tid];     Bnh[0] = bh0[2*HID+tid];
  Br[1] = bi1[tid] + bh1[tid]; Bz[1] = bi1[HID+tid] + bh1[HID+tid];
  Bni[1] = bi1[2*HID+tid];     Bnh[1] = bh1[2*HID+tid];
  Br[2] = bi2[tid] + bh2[tid]; Bz[2] = bi2[HID+tid] + bh2[HID+tid];
  Bni[2] = bi2[2*HID+tid];     Bnh[2] = bh2[2*HID+tid];
  Br[3] = bi3[tid] + bh3[tid]; Bz[3] = bi3[HID+tid] + bh3[HID+tid];
  Bni[3] = bi3[2*HID+tid];     Bnh[3] = bh3[2*HID+tid];
  Br[4] = bi4[tid] + bh4[tid]; Bz[4] = bi4[HID+tid] + bh4[HID+tid];
  Bni[4] = bi4[2*HID+tid];     Bnh[4] = bh4[2*HID+tid];
  float wo0 = 0.f, wo1 = 0.f, wo2 = 0.f, wo3 = 0.f;
  const float bo0 = bo[0];
  if (wave == 0) { wo0 = Wo[lane]; wo1 = Wo[64+lane]; wo2 = Wo[128+lane]; wo3 = Wo[192+lane]; }
  kst[tid] = 0.f;
  __syncthreads();

  for (int t = 0; t < SEQT; ++t) {
    if (tid == 0) { red[1] = 0.f; red[2] = -3.0e38f; }
    float ctxa = 0.f;
    // ---- flash attention over mem[b], 8 tiles of 64 positions ----
    for (int tile = 0; tile < 8; ++tile) {
      const u16* src = mem + ((size_t)b * SEQT + tile * 64) * HID;
      u16x8 v[8];
      #pragma unroll
      for (int i = 0; i < 8; ++i)
        v[i] = __builtin_nontemporal_load((const u16x8*)(src + i * 2048 + tid * 8));
      __syncthreads();             // WAR: previous tile's ctx reads of L done; red init visible
      {
        u32* L32 = (u32*)L;
        const int r0 = tid >> 5;
        const int cd = (tid & 31) * 4;
        #pragma unroll
        for (int i = 0; i < 8; ++i) {
          u32x4 w = __builtin_bit_cast(u32x4, v[i]);
          int base = (i * 8 + r0) * 131 + cd;
          L32[base + 0] = w.x; L32[base + 1] = w.y;
          L32[base + 2] = w.z; L32[base + 3] = w.w;
        }
      }
      __syncthreads();             // tile staged
      // scores: thread (ss,sq) dots 4 sub-chunks of 16 h
      float acc = 0.f;
      #pragma unroll
      for (int ii = 0; ii < 4; ++ii) {
        const u16* Lr = &L[ss * LSTR + sq * 16 + ii * 64];
        const float* kr = &kst[sq * 16 + ii * 64];
        #pragma unroll
        for (int j = 0; j < 16; ++j)
          acc += bf2f(Lr[j]) * kr[j];
      }
      acc += __shfl_xor(acc, 1);
      acc += __shfl_xor(acc, 2);
      if (sq == 0) sc[ss] = acc;
      __syncthreads();             // scores ready
      // online softmax update (wave 0)
      if (wave == 0) {
        float mt = sc[lane];
        #pragma unroll
        for (int off = 32; off; off >>= 1) mt = fmaxf(mt, __shfl_xor(mt, off));
        float m_old = red[2];
        float m_new = fmaxf(m_old, mt);
        float p = __expf(sc[lane] - m_new);
        pp[lane] = p;
        float lt = p;
        #pragma unroll
        for (int off = 32; off; off >>= 1) lt += __shfl_xor(lt, off);
        if (lane == 0) {
          red[0] = __expf(m_old - m_new);   // alpha (first tile: exp(-inf)=0)
          red[1] = red[1] * red[0] + lt;
          red[2] = m_new;
        }
      }
      __syncthreads();             // pp / alpha ready
      float alpha = red[0];
      const u16* Lc = &L[tid];
      float accc = 0.f;
      #pragma unroll 8
      for (int s = 0; s < 64; ++s)
        accc += pp[s] * bf2f(Lc[s * LSTR]);
      ctxa = ctxa * alpha + accc;
    }
    // ---- build d = [x_t, ctx] ----
    float linv = 1.f / red[1];
    dv[DIM + tid] = ctxa * linv;
    if (tid < DIM)
      dv[tid] = __builtin_nontemporal_load(x + ((size_t)b * SEQT + t) * DIM + tid);
    __syncthreads();
    // ---- 5 feed-forward GRU cells ----
    float h0 = cell_fwd<DIM + HID>(dv,   W0b, tid, Br[0], Bz[0], Bni[0], Bnh[0]);
    hb[0][tid] = h0; __syncthreads();
    float h1 = cell_fwd<HID>(hb[0], W1b, tid, Br[1], Bz[1], Bni[1], Bnh[1]);
    hb[1][tid] = h1; __syncthreads();
    float h2 = cell_fwd<HID>(hb[1], W2b, tid, Br[2], Bz[2], Bni[2], Bnh[2]);
    hb[0][tid] = h2; __syncthreads();
    float h3 = cell_fwd<HID>(hb[0], W3b, tid, Br[3], Bz[3], Bni[3], Bnh[3]);
    hb[1][tid] = h3; __syncthreads();
    float h4 = cell_fwd<HID>(hb[1], W4b, tid, Br[4], Bz[4], Bni[4], Bnh[4]);
    kst[tid] = h4;
    __syncthreads();               // kst stable for output dot and next step's scores
    // ---- output layer (wave 0) ----
    if (wave == 0) {
      float acc = kst[lane] * wo0 + kst[64 + lane] * wo1 +
                  kst[128 + lane] * wo2 + kst[192 + lane] * wo3;
      #pragma unroll
      for (int off = 32; off; off >>= 1) acc += __shfl_xor(acc, off);
      if (lane == 0) out[(size_t)b * SEQT + t] = sigm(acc + bo0);
    }
  }
}

// ---------------- host ----------------
extern "C" void kernel_launch(void* const* d_in, const int* in_sizes, int n_in,
                              void* d_out, int out_size, void* d_ws, size_t ws_size,
                              hipStream_t stream) {
  const float* x    = (const float*)d_in[0];
  const float* Wmi  = (const float*)d_in[1];
  const float* Wmh  = (const float*)d_in[2];
  const float* bmi  = (const float*)d_in[3];
  const float* bmh  = (const float*)d_in[4];
  const float* Wd0  = (const float*)d_in[5];
  const float* bi0  = (const float*)d_in[6];
  const float* bh0  = (const float*)d_in[7];
  const float* Wd1  = (const float*)d_in[8];
  const float* bi1  = (const float*)d_in[9];
  const float* bh1  = (const float*)d_in[10];
  const float* Wd2  = (const float*)d_in[11];
  const float* bi2  = (const float*)d_in[12];
  const float* bh2  = (const float*)d_in[13];
  const float* Wk0  = (const float*)d_in[14];
  const float* bik0 = (const float*)d_in[15];
  const float* bhk0 = (const float*)d_in[16];
  const float* Wk1  = (const float*)d_in[17];
  const float* bik1 = (const float*)d_in[18];
  const float* bhk1 = (const float*)d_in[19];
  const float* Wo   = (const float*)d_in[20];
  const float* bo   = (const float*)d_in[21];

  u16* mem = (u16*)d_ws;
  size_t off = (size_t)BATCH * SEQT * HID;     // u16 units
  u16* Wmib = mem + off; off += (size_t)G3 * DIM;
  u16* Wmhb = mem + off; off += (size_t)G3 * HID;
  u16* W0b  = mem + off; off += (size_t)G3 * (DIM + HID);
  u16* W1b  = mem + off; off += (size_t)G3 * HID;
  u16* W2b  = mem + off; off += (size_t)G3 * HID;
  u16* W3b  = mem + off; off += (size_t)G3 * HID;
  u16* W4b  = mem + off; off += (size_t)G3 * HID;
  (void)ws_size; (void)in_sizes; (void)n_in; (void)out_size;

  convertk<<<(G3*DIM + 255) / 256, 256, 0, stream>>>(Wmi, Wmib, G3*DIM);
  convertk<<<(G3*HID + 255) / 256, 256, 0, stream>>>(Wmh, Wmhb, G3*HID);
  convertk<<<(G3*(DIM+HID) + 255) / 256, 256, 0, stream>>>(Wd0, W0b, G3*(DIM+HID));
  convertk<<<(G3*HID + 255) / 256, 256, 0, stream>>>(Wd1, W1b, G3*HID);
  convertk<<<(G3*HID + 255) / 256, 256, 0, stream>>>(Wd2, W2b, G3*HID);
  convertk<<<(G3*HID + 255) / 256, 256, 0, stream>>>(Wk0, W3b, G3*HID);
  convertk<<<(G3*HID + 255) / 256, 256, 0, stream>>>(Wk1, W4b, G3*HID);

  gru_mem<<<BATCH, 256, 0, stream>>>(x, Wmib, Wmhb, bmi, bmh, mem);
  decoder<<<BATCH, 256, 0, stream>>>(x, mem, W0b, W1b, W2b, W3b, W4b,
                                     bi0, bh0, bi1, bh1, bi2, bh2,
                                     bik0, bhk0, bik1, bhk1, Wo, bo,
                                     (float*)d_out);
}

// Round 2
// 49337.579 us; speedup vs baseline: 1.8390x; 1.8390x over previous
//
#include <hip/hip_runtime.h>
#include <stdint.h>

#define BATCH 256
#define SEQT  512
#define DIM   128
#define HID   256
#define G3    768   // 3*HID
#define LSTR  264   // u16 stride: 132 dwords, 16B-aligned rows, PV reads 2-way-bank (free)

typedef unsigned short u16;
typedef unsigned int   u32;
typedef u16 u16x8 __attribute__((ext_vector_type(8)));

static __device__ __forceinline__ float bflo(u32 w) { return __builtin_bit_cast(float, w << 16); }
static __device__ __forceinline__ float bfhi(u32 w) { return __builtin_bit_cast(float, w & 0xFFFF0000u); }
static __device__ __forceinline__ float bf2f(u16 u) {
  u32 v = ((u32)u) << 16;
  return __builtin_bit_cast(float, v);
}
static __device__ __forceinline__ u16 f2bf(float f) {
  u32 x = __builtin_bit_cast(u32, f);
  x += 0x7FFFu + ((x >> 16) & 1u);
  return (u16)(x >> 16);
}
static __device__ __forceinline__ float sigm(float v) {
  return 1.f / (1.f + __expf(-v));
}

// 8-element bf16·f32 dot accumulate; w as packed pairs -> 1 shift or 1 and per element
static __device__ __forceinline__ void dot8(float& acc, u16x8 wv, float4 a, float4 b) {
  u32 w0 = (u32)wv[0] | ((u32)wv[1] << 16);
  u32 w1 = (u32)wv[2] | ((u32)wv[3] << 16);
  u32 w2 = (u32)wv[4] | ((u32)wv[5] << 16);
  u32 w3 = (u32)wv[6] | ((u32)wv[7] << 16);
  acc += bflo(w0) * a.x; acc += bfhi(w0) * a.y;
  acc += bflo(w1) * a.z; acc += bfhi(w1) * a.w;
  acc += bflo(w2) * b.x; acc += bfhi(w2) * b.y;
  acc += bflo(w3) * b.z; acc += bfhi(w3) * b.w;
}

// ---------------- weight fp32 -> bf16 conversion ----------------
__global__ void convertk(const float* __restrict__ src, u16* __restrict__ dst, int n) {
  int i = blockIdx.x * 256 + threadIdx.x;
  if (i < n) dst[i] = f2bf(src[i]);
}

// ---------------- phase B: memory GRU, one workgroup per batch row ----------------
__launch_bounds__(256, 1)
__global__ void gru_mem(const float* __restrict__ x,
                        const u16* __restrict__ Wib, const u16* __restrict__ Whb,
                        const float* __restrict__ bmi, const float* __restrict__ bmh,
                        u16* __restrict__ mem) {
  const int b = blockIdx.x, tid = threadIdx.x;
  __shared__ __align__(16) float hs[HID];
  __shared__ __align__(16) float xs[DIM];
  const float bir = bmi[tid],      biz = bmi[HID + tid],  bin = bmi[2*HID + tid];
  const float bhr = bmh[tid],      bhz = bmh[HID + tid],  bhn = bmh[2*HID + tid];
  const u16x8* wir = (const u16x8*)(Wib + (size_t)tid * DIM);
  const u16x8* wiz = (const u16x8*)(Wib + (size_t)(HID + tid) * DIM);
  const u16x8* win = (const u16x8*)(Wib + (size_t)(2*HID + tid) * DIM);
  const u16x8* whr = (const u16x8*)(Whb + (size_t)tid * HID);
  const u16x8* whz = (const u16x8*)(Whb + (size_t)(HID + tid) * HID);
  const u16x8* whn = (const u16x8*)(Whb + (size_t)(2*HID + tid) * HID);
  const float4* xs4 = (const float4*)xs;
  const float4* hs4 = (const float4*)hs;
  hs[tid] = 0.f;
  float hprev = 0.f;
  __syncthreads();
  for (int t = 0; t < SEQT; ++t) {
    if (tid < DIM)
      xs[tid] = __builtin_nontemporal_load(x + ((size_t)b * SEQT + t) * DIM + tid);
    __syncthreads();
    float air = 0.f, aiz = 0.f, ain = 0.f;
    #pragma unroll 8
    for (int j = 0; j < DIM / 8; ++j) {
      u16x8 wa = wir[j], wb = wiz[j], wc = win[j];
      float4 xa = xs4[2*j], xb = xs4[2*j+1];
      dot8(air, wa, xa, xb);
      dot8(aiz, wb, xa, xb);
      dot8(ain, wc, xa, xb);
    }
    float ahr = 0.f, ahz = 0.f, ahn = 0.f;
    #pragma unroll 8
    for (int j = 0; j < HID / 8; ++j) {
      u16x8 wa = whr[j], wb = whz[j], wc = whn[j];
      float4 ha = hs4[2*j], hbv = hs4[2*j+1];
      dot8(ahr, wa, ha, hbv);
      dot8(ahz, wb, ha, hbv);
      dot8(ahn, wc, ha, hbv);
    }
    float r = sigm(air + bir + ahr + bhr);
    float z = sigm(aiz + biz + ahz + bhz);
    float n = tanhf(ain + bin + r * (ahn + bhn));
    float hnew = (1.f - z) * n + z * hprev;
    __syncthreads();               // all reads of hs done
    hs[tid] = hnew;
    hprev = hnew;
    mem[((size_t)b * SEQT + t) * HID + tid] = f2bf(hnew);
    __syncthreads();               // hs ready
  }
}

// ---------------- GRU cell with h=0 (feed-forward): thread owns gate rows tid, H+tid, 2H+tid ----------------
template <int IN>
static __device__ __forceinline__ float cell_fwd(const float* __restrict__ in,
                                                 const u16* __restrict__ Wb, int tid,
                                                 float br_, float bz_, float bni, float bnh) {
  const u16x8* wr = (const u16x8*)(Wb + (size_t)tid * IN);
  const u16x8* wz = (const u16x8*)(Wb + (size_t)(HID + tid) * IN);
  const u16x8* wn = (const u16x8*)(Wb + (size_t)(2*HID + tid) * IN);
  const float4* in4 = (const float4*)in;
  float ar = 0.f, az = 0.f, an = 0.f;
  #pragma unroll 8
  for (int j = 0; j < IN / 8; ++j) {
    u16x8 wa = wr[j], wb = wz[j], wc = wn[j];
    float4 xa = in4[2*j], xb = in4[2*j+1];
    dot8(ar, wa, xa, xb);
    dot8(az, wb, xa, xb);
    dot8(an, wc, xa, xb);
  }
  float r = sigm(ar + br_);
  float z = sigm(az + bz_);
  float n = tanhf(an + bni + r * bnh);
  return (1.f - z) * n;
}

// ---------------- phase C: decoder scan, one workgroup per batch row ----------------
__launch_bounds__(256, 1)
__global__ void decoder(const float* __restrict__ x, const u16* __restrict__ mem,
                        const u16* __restrict__ W0b, const u16* __restrict__ W1b,
                        const u16* __restrict__ W2b, const u16* __restrict__ W3b,
                        const u16* __restrict__ W4b,
                        const float* __restrict__ bi0, const float* __restrict__ bh0,
                        const float* __restrict__ bi1, const float* __restrict__ bh1,
                        const float* __restrict__ bi2, const float* __restrict__ bh2,
                        const float* __restrict__ bi3, const float* __restrict__ bh3,
                        const float* __restrict__ bi4, const float* __restrict__ bh4,
                        const float* __restrict__ Wo, const float* __restrict__ bo,
                        float* __restrict__ out) {
  const int b = blockIdx.x, tid = threadIdx.x;
  const int lane = tid & 63, wave = tid >> 6;
  __shared__ __align__(16) u16 L[64 * LSTR];       // one 64x256 bf16 mem tile
  __shared__ __align__(16) float pp[512];          // softmax numerators
  __shared__ __align__(16) float pvp[2][256];      // PV partials (s-halves)
  __shared__ __align__(16) float kst[HID];
  __shared__ __align__(16) float dv[DIM + HID];
  __shared__ __align__(16) float hb[2][HID];
  __shared__ float red[8];

  float Br[5], Bz[5], Bni[5], Bnh[5];
  Br[0] = bi0[tid] + bh0[tid]; Bz[0] = bi0[HID+tid] + bh0[HID+tid];
  Bni[0] = bi0[2*HID+tid];     Bnh[0] = bh0[2*HID+tid];
  Br[1] = bi1[tid] + bh1[tid]; Bz[1] = bi1[HID+tid] + bh1[HID+tid];
  Bni[1] = bi1[2*HID+tid];     Bnh[1] = bh1[2*HID+tid];
  Br[2] = bi2[tid] + bh2[tid]; Bz[2] = bi2[HID+tid] + bh2[HID+tid];
  Bni[2] = bi2[2*HID+tid];     Bnh[2] = bh2[2*HID+tid];
  Br[3] = bi3[tid] + bh3[tid]; Bz[3] = bi3[HID+tid] + bh3[HID+tid];
  Bni[3] = bi3[2*HID+tid];     Bnh[3] = bh3[2*HID+tid];
  Br[4] = bi4[tid] + bh4[tid]; Bz[4] = bi4[HID+tid] + bh4[HID+tid];
  Bni[4] = bi4[2*HID+tid];     Bnh[4] = bh4[2*HID+tid];
  float wo0 = 0.f, wo1 = 0.f, wo2 = 0.f, wo3 = 0.f;
  const float bo0 = bo[0];
  if (wave == 0) { wo0 = Wo[lane]; wo1 = Wo[64+lane]; wo2 = Wo[128+lane]; wo3 = Wo[192+lane]; }
  kst[tid] = 0.f;
  __syncthreads();

  const int ch = tid & 127;          // PV column-pair index
  const int c0 = ch * 2;
  const int shalf = tid >> 7;        // PV s-half

  for (int t = 0; t < SEQT; ++t) {
    // x prefetch into dv (independent of attention)
    if (tid < DIM)
      dv[tid] = __builtin_nontemporal_load(x + ((size_t)b * SEQT + t) * DIM + tid);

    // ---- pass 1: all 512 scores from global (L2-hot), thread owns positions tid, tid+256 ----
    const u16x8* m0 = (const u16x8*)(mem + ((size_t)b * SEQT + tid) * HID);
    const u16x8* m1 = (const u16x8*)(mem + ((size_t)b * SEQT + 256 + tid) * HID);
    const float4* k4 = (const float4*)kst;
    float s0 = 0.f, s1 = 0.f;
    #pragma unroll 8
    for (int j = 0; j < HID / 8; ++j) {
      u16x8 a = m0[j], c = m1[j];
      float4 ka = k4[2*j], kb = k4[2*j+1];
      dot8(s0, a, ka, kb);
      dot8(s1, c, ka, kb);
    }
    // ---- softmax: block max, exp, block sum ----
    float mloc = fmaxf(s0, s1);
    #pragma unroll
    for (int off = 32; off; off >>= 1) mloc = fmaxf(mloc, __shfl_xor(mloc, off));
    if (lane == 0) red[wave] = mloc;
    __syncthreads();
    float m = fmaxf(fmaxf(red[0], red[1]), fmaxf(red[2], red[3]));
    float p0 = __expf(s0 - m), p1 = __expf(s1 - m);
    pp[tid] = p0; pp[256 + tid] = p1;
    float lloc = p0 + p1;
    #pragma unroll
    for (int off = 32; off; off >>= 1) lloc += __shfl_xor(lloc, off);
    if (lane == 0) red[4 + wave] = lloc;
    __syncthreads();
    const float linv = 1.f / (red[4] + red[5] + red[6] + red[7]);

    // ---- pass 2: PV over 8 staged tiles; thread owns cols c0,c0+1 for its s-half ----
    float ctx0 = 0.f, ctx1 = 0.f;
    for (int tile = 0; tile < 8; ++tile) {
      const u16x8* src = (const u16x8*)(mem + ((size_t)b * SEQT + tile * 64) * HID);
      u16x8 v[8];
      #pragma unroll
      for (int i = 0; i < 8; ++i) v[i] = src[tid + i * 256];   // coalesced
      __syncthreads();             // prior reads of L complete
      #pragma unroll
      for (int i = 0; i < 8; ++i) {
        int c = tid + i * 256;
        *(u16x8*)(L + (c >> 5) * LSTR + (c & 31) * 8) = v[i];  // ds_write_b128
      }
      __syncthreads();             // tile staged
      const float4* p4 = (const float4*)(pp + tile * 64 + shalf * 32);
      const u16* Lb = L + (size_t)shalf * 32 * LSTR + c0;
      #pragma unroll
      for (int g = 0; g < 8; ++g) {
        float4 pv = p4[g];
        u32 w0 = *(const u32*)(Lb + (4*g+0) * LSTR);
        u32 w1 = *(const u32*)(Lb + (4*g+1) * LSTR);
        u32 w2 = *(const u32*)(Lb + (4*g+2) * LSTR);
        u32 w3 = *(const u32*)(Lb + (4*g+3) * LSTR);
        ctx0 += pv.x * bflo(w0); ctx1 += pv.x * bfhi(w0);
        ctx0 += pv.y * bflo(w1); ctx1 += pv.y * bfhi(w1);
        ctx0 += pv.z * bflo(w2); ctx1 += pv.z * bfhi(w2);
        ctx0 += pv.w * bflo(w3); ctx1 += pv.w * bfhi(w3);
      }
    }
    pvp[shalf][c0]     = ctx0;
    pvp[shalf][c0 + 1] = ctx1;
    __syncthreads();
    dv[DIM + tid] = (pvp[0][tid] + pvp[1][tid]) * linv;
    __syncthreads();

    // ---- 5 feed-forward GRU cells ----
    float h0 = cell_fwd<DIM + HID>(dv,   W0b, tid, Br[0], Bz[0], Bni[0], Bnh[0]);
    hb[0][tid] = h0; __syncthreads();
    float h1 = cell_fwd<HID>(hb[0], W1b, tid, Br[1], Bz[1], Bni[1], Bnh[1]);
    hb[1][tid] = h1; __syncthreads();
    float h2 = cell_fwd<HID>(hb[1], W2b, tid, Br[2], Bz[2], Bni[2], Bnh[2]);
    hb[0][tid] = h2; __syncthreads();
    float h3 = cell_fwd<HID>(hb[0], W3b, tid, Br[3], Bz[3], Bni[3], Bnh[3]);
    hb[1][tid] = h3; __syncthreads();
    float h4 = cell_fwd<HID>(hb[1], W4b, tid, Br[4], Bz[4], Bni[4], Bnh[4]);
    kst[tid] = h4;
    __syncthreads();               // kst stable for out + next step's scores
    // ---- output layer (wave 0) ----
    if (wave == 0) {
      float acc = kst[lane] * wo0 + kst[64 + lane] * wo1 +
                  kst[128 + lane] * wo2 + kst[192 + lane] * wo3;
      #pragma unroll
      for (int off = 32; off; off >>= 1) acc += __shfl_xor(acc, off);
      if (lane == 0) out[(size_t)b * SEQT + t] = sigm(acc + bo0);
    }
  }
}

// ---------------- host ----------------
extern "C" void kernel_launch(void* const* d_in, const int* in_sizes, int n_in,
                              void* d_out, int out_size, void* d_ws, size_t ws_size,
                              hipStream_t stream) {
  const float* x    = (const float*)d_in[0];
  const float* Wmi  = (const float*)d_in[1];
  const float* Wmh  = (const float*)d_in[2];
  const float* bmi  = (const float*)d_in[3];
  const float* bmh  = (const float*)d_in[4];
  const float* Wd0  = (const float*)d_in[5];
  const float* bi0  = (const float*)d_in[6];
  const float* bh0  = (const float*)d_in[7];
  const float* Wd1  = (const float*)d_in[8];
  const float* bi1  = (const float*)d_in[9];
  const float* bh1  = (const float*)d_in[10];
  const float* Wd2  = (const float*)d_in[11];
  const float* bi2  = (const float*)d_in[12];
  const float* bh2  = (const float*)d_in[13];
  const float* Wk0  = (const float*)d_in[14];
  const float* bik0 = (const float*)d_in[15];
  const float* bhk0 = (const float*)d_in[16];
  const float* Wk1  = (const float*)d_in[17];
  const float* bik1 = (const float*)d_in[18];
  const float* bhk1 = (const float*)d_in[19];
  const float* Wo   = (const float*)d_in[20];
  const float* bo   = (const float*)d_in[21];

  u16* mem = (u16*)d_ws;
  size_t off = (size_t)BATCH * SEQT * HID;     // u16 units
  u16* Wmib = mem + off; off += (size_t)G3 * DIM;
  u16* Wmhb = mem + off; off += (size_t)G3 * HID;
  u16* W0b  = mem + off; off += (size_t)G3 * (DIM + HID);
  u16* W1b  = mem + off; off += (size_t)G3 * HID;
  u16* W2b  = mem + off; off += (size_t)G3 * HID;
  u16* W3b  = mem + off; off += (size_t)G3 * HID;
  u16* W4b  = mem + off; off += (size_t)G3 * HID;
  (void)ws_size; (void)in_sizes; (void)n_in; (void)out_size;

  convertk<<<(G3*DIM + 255) / 256, 256, 0, stream>>>(Wmi, Wmib, G3*DIM);
  convertk<<<(G3*HID + 255) / 256, 256, 0, stream>>>(Wmh, Wmhb, G3*HID);
  convertk<<<(G3*(DIM+HID) + 255) / 256, 256, 0, stream>>>(Wd0, W0b, G3*(DIM+HID));
  convertk<<<(G3*HID + 255) / 256, 256, 0, stream>>>(Wd1, W1b, G3*HID);
  convertk<<<(G3*HID + 255) / 256, 256, 0, stream>>>(Wd2, W2b, G3*HID);
  convertk<<<(G3*HID + 255) / 256, 256, 0, stream>>>(Wk0, W3b, G3*HID);
  convertk<<<(G3*HID + 255) / 256, 256, 0, stream>>>(Wk1, W4b, G3*HID);

  gru_mem<<<BATCH, 256, 0, stream>>>(x, Wmib, Wmhb, bmi, bmh, mem);
  decoder<<<BATCH, 256, 0, stream>>>(x, mem, W0b, W1b, W2b, W3b, W4b,
                                     bi0, bh0, bi1, bh1, bi2, bh2,
                                     bik0, bhk0, bik1, bhk1, Wo, bo,
                                     (float*)d_out);
}